// Round 14
// baseline (385.827 us; speedup 1.0000x reference)
//
#include <hip/hip_runtime.h>

#define NA 100000
#define NB 100000
#define NEDGE 1600000
#define HD 128
#define OUTD 16
#define NG 256
#define DA 64
#define DB 32

#define BIN_SHIFT 9
#define BIN_W 512
#define NBINS_R 196              // ceil(100000/512)
#define NBINS 588                // 3 relations
#define PADBIN 10240             // padded slot per bin (~+23 sigma)
#define EPB 8192                 // edges per block in part
#define ECHUNKS 196              // ceil(NEDGE/EPB)
#define GBW 256                  // nodes per gather block (half-bin)
#define EHALF 5632               // edge capacity per half-bin (mean 4096, +24 sigma)

typedef unsigned int uint_t;
typedef unsigned short ushort_t;
typedef unsigned char uchar_t;
typedef __bf16 bf16_t;
typedef bf16_t bf16x8 __attribute__((ext_vector_type(8)));
typedef float f32x4 __attribute__((ext_vector_type(4)));
typedef float f32x2 __attribute__((ext_vector_type(2)));

__device__ __forceinline__ float bflo(uint_t u) {
    union { uint_t i; float f; } c; c.i = u << 16; return c.f;
}
__device__ __forceinline__ float bfhi(uint_t u) {
    union { uint_t i; float f; } c; c.i = u & 0xffff0000u; return c.f;
}
__device__ __forceinline__ float bf2f(ushort_t u) {
    union { uint_t i; float f; } c; c.i = ((uint_t)u) << 16; return c.f;
}
__device__ __forceinline__ uint_t f2bf(float f) {
    union { float f; uint_t i; } c; c.f = f;
    uint_t r = c.i + 0x7FFFu + ((c.i >> 16) & 1u);
    return r >> 16;
}
__device__ __forceinline__ uint_t pack2bf(float lo, float hi) {
    return f2bf(lo) | (f2bf(hi) << 16);
}
__device__ __forceinline__ uchar_t f2fp8(float v) {
    return (uchar_t)(__builtin_amdgcn_cvt_pk_fp8_f32(v, v, 0, false) & 0xff);
}

// ---------------- weight prep (FRAGMENT-MAJOR, col-half split) + bias_pa + gcount -
__global__ void __launch_bounds__(256)
prep_misc_kernel(const float* __restrict__ Wl_ab, const float* __restrict__ Wr_ab,
                 const float* __restrict__ Wl_ba, const float* __restrict__ Wl_aa,
                 const float* __restrict__ Wr_ba, const float* __restrict__ Wr_aa,
                 const float* __restrict__ Wemb_a, const float* __restrict__ Wemb_b,
                 ushort_t* __restrict__ wt_fb, ushort_t* __restrict__ wt_pa,
                 ushort_t* __restrict__ wt_ea, ushort_t* __restrict__ wt_eb,
                 const float* __restrict__ bl_ba, const float* __restrict__ bl_aa,
                 float* __restrict__ bias_pa,
                 const int* __restrict__ batch_a, const int* __restrict__ batch_b,
                 float* __restrict__ ga, float* __restrict__ gb)
{
    const int bx = blockIdx.x;
    __align__(16) ushort_t tmp[8];
    if (bx >= 40) {
        if (bx <= 43) {                          // Wemb_a, K=64, frag-major full width
            const int id = (bx - 40) * 256 + threadIdx.x;
            const int kk = id >> 9, ni = (id >> 6) & 7, l = id & 63;
            const int col = ni * 16 + (l & 15);
            const int k0 = kk * 32 + (l >> 4) * 8;
#pragma unroll
            for (int j = 0; j < 8; ++j) tmp[j] = (ushort_t)f2bf(Wemb_a[(k0 + j) * HD + col]);
            *reinterpret_cast<uint4*>(wt_ea + (size_t)id * 8) = *reinterpret_cast<const uint4*>(tmp);
            return;
        }
        if (bx <= 45) {                          // Wemb_b, K=32, frag-major full width
            const int id = (bx - 44) * 256 + threadIdx.x;
            const int ni = id >> 6, l = id & 63;
            const int col = ni * 16 + (l & 15);
            const int k0 = (l >> 4) * 8;
#pragma unroll
            for (int j = 0; j < 8; ++j) tmp[j] = (ushort_t)f2bf(Wemb_b[(k0 + j) * HD + col]);
            *reinterpret_cast<uint4*>(wt_eb + (size_t)id * 8) = *reinterpret_cast<const uint4*>(tmp);
            return;
        }
        if (bx == 46) {
            if (threadIdx.x < HD) bias_pa[threadIdx.x] = bl_ba[threadIdx.x] + bl_aa[threadIdx.x];
            return;
        }
        // gcount via binary search (batch sorted)
        const int g = threadIdx.x;
        const int* batch = (bx == 48) ? batch_b : batch_a;
        float* outp = (bx == 48) ? gb : ga;
        const int n = NA;
        int lo0 = 0, hi0 = n;
        while (lo0 < hi0) { const int mid = (lo0 + hi0) >> 1; if (batch[mid] < g) lo0 = mid + 1; else hi0 = mid; }
        int lo1 = 0, hi1 = n;
        while (lo1 < hi1) { const int mid = (lo1 + hi1) >> 1; if (batch[mid] < g + 1) lo1 = mid + 1; else hi1 = mid; }
        outp[g] = (float)(lo1 - lo0);
        return;
    }
    const int m = bx >> 3;
    const int id = (bx & 7) * 256 + threadIdx.x;   // 0..2047
    const int kk = id >> 9, ni = (id >> 6) & 7, l = id & 63;
    const int col = ni * 16 + (l & 15);
    const int k0 = kk * 32 + (l >> 4) * 8;
    const float* src = (m == 0) ? Wl_ab : (m == 1) ? Wr_ab : (m == 2) ? Wl_ba
                     : (m == 3) ? Wl_aa : Wr_ba;
#pragma unroll
    for (int j = 0; j < 8; ++j) {
        float v = src[(k0 + j) * HD + col];
        if (m == 4) v += Wr_aa[(k0 + j) * HD + col];
        tmp[j] = (ushort_t)f2bf(v);
    }
    const int half = ni >> 2, nih = ni & 3;
    const size_t eoff = (size_t)half * 8192 + ((kk * 4 + nih) * 64 + l) * 8;
    ushort_t* dst = (m < 2) ? (wt_fb + (size_t)m * 16384) : (wt_pa + (size_t)(m - 2) * 16384);
    *reinterpret_cast<uint4*>(dst + eoff) = *reinterpret_cast<const uint4*>(tmp);
}

// ---------------- MFMA input embedding, W in LDS; writes bf16 h AND fp8 h8 --------
template<int K>
__device__ __forceinline__ void
emb_body(const float* __restrict__ x, const ushort_t* __restrict__ wtf,
         const float* __restrict__ bias, ushort_t* __restrict__ h,
         uchar_t* __restrict__ h8, int n, ushort_t* wlds)
{
    constexpr int KST = K / 32;
    for (int i = threadIdx.x * 8; i < K * HD; i += 2048)
        *reinterpret_cast<uint4*>(wlds + i) = *reinterpret_cast<const uint4*>(wtf + i);
    __syncthreads();

    const int l = threadIdx.x & 63, w = threadIdx.x >> 6;
    const int lo = l & 15, hi = l >> 4;
    const int row_base = blockIdx.x * 128 + w * 32;

    f32x4 acc[2][8];
    const f32x4 zero = {0.f, 0.f, 0.f, 0.f};
#pragma unroll
    for (int mi = 0; mi < 2; ++mi)
#pragma unroll
        for (int ni = 0; ni < 8; ++ni) acc[mi][ni] = zero;

    bf16x8 a[2][KST];
#pragma unroll
    for (int mi = 0; mi < 2; ++mi) {
        int r = row_base + mi * 16 + lo;
        r = min(r, n - 1);
        const float* xr = x + (size_t)r * K + hi * 8;
#pragma unroll
        for (int kk = 0; kk < KST; ++kk) {
            const float4 f0 = *reinterpret_cast<const float4*>(xr + kk * 32);
            const float4 f1 = *reinterpret_cast<const float4*>(xr + kk * 32 + 4);
            __align__(16) ushort_t us[8];
            us[0] = (ushort_t)f2bf(f0.x); us[1] = (ushort_t)f2bf(f0.y);
            us[2] = (ushort_t)f2bf(f0.z); us[3] = (ushort_t)f2bf(f0.w);
            us[4] = (ushort_t)f2bf(f1.x); us[5] = (ushort_t)f2bf(f1.y);
            us[6] = (ushort_t)f2bf(f1.z); us[7] = (ushort_t)f2bf(f1.w);
            a[mi][kk] = *reinterpret_cast<const bf16x8*>(us);
        }
    }
#pragma unroll
    for (int kk = 0; kk < KST; ++kk) {
#pragma unroll
        for (int ni = 0; ni < 8; ++ni) {
            const bf16x8 b = *reinterpret_cast<const bf16x8*>(wlds + ((kk * 8 + ni) * 64 + l) * 8);
            acc[0][ni] = __builtin_amdgcn_mfma_f32_16x16x32_bf16(a[0][kk], b, acc[0][ni], 0, 0, 0);
            acc[1][ni] = __builtin_amdgcn_mfma_f32_16x16x32_bf16(a[1][kk], b, acc[1][ni], 0, 0, 0);
        }
    }
#pragma unroll
    for (int ni = 0; ni < 8; ++ni) {
        const int col = ni * 16 + lo;
        const float bv = bias[col];
#pragma unroll
        for (int mi = 0; mi < 2; ++mi) {
            const f32x4 v = acc[mi][ni];
#pragma unroll
            for (int r = 0; r < 4; ++r) {
                const int row = row_base + mi * 16 + hi * 4 + r;
                if (row < n) {
                    const float val = v[r] + bv;
                    h[(size_t)row * HD + col] = (ushort_t)f2bf(val);
                    h8[(size_t)row * HD + col] = f2fp8(val);
                }
            }
        }
    }
}

__global__ void __launch_bounds__(256)
emb2_kernel(const float* __restrict__ x_a, const float* __restrict__ x_b,
            const ushort_t* __restrict__ wt_ea, const ushort_t* __restrict__ wt_eb,
            const float* __restrict__ bemb_a, const float* __restrict__ bemb_b,
            ushort_t* __restrict__ h_a, ushort_t* __restrict__ h_b,
            uchar_t* __restrict__ h8_a, uchar_t* __restrict__ h8_b)
{
    __shared__ ushort_t wlds[DA * HD];   // 16 KB (max of the two)
    if (blockIdx.y == 0) emb_body<DA>(x_a, wt_ea, bemb_a, h_a, h8_a, NA, wlds);
    else                 emb_body<DB>(x_b, wt_eb, bemb_b, h_b, h8_b, NB, wlds);
}

// ---------------- partition into PADDED per-bin slots (LDS-staged, coalesced) -----
// packed entry: (dst&511)<<17 | src   (src < 2^17)
__global__ void __launch_bounds__(256)
part3_kernel(const int* __restrict__ ei_ab, const int* __restrict__ ei_ba,
             const int* __restrict__ ei_aa, int* __restrict__ bincnt,
             uint_t* __restrict__ binned)
{
    __shared__ uint_t sorted[EPB];         // 32 KB
    __shared__ int lh[NBINS_R];
    __shared__ int lbase[NBINS_R];
    __shared__ int gbase[NBINS_R];
    __shared__ int lcur[NBINS_R];
    __shared__ int sc[256];
    const int r = blockIdx.y;
    const int* ei = (r == 0) ? ei_ab : (r == 1) ? ei_ba : ei_aa;
    const int t = threadIdx.x;
    for (int i = t; i < NBINS_R; i += 256) lh[i] = 0;
    __syncthreads();
    const int e0 = blockIdx.x * EPB;
    const int e1 = min(e0 + EPB, NEDGE);
    for (int e = e0 + t; e < e1; e += 256)
        atomicAdd(&lh[ei[NEDGE + e] >> BIN_SHIFT], 1);
    __syncthreads();
    {
        const int v = (t < NBINS_R) ? lh[t] : 0;
        sc[t] = v; __syncthreads();
        for (int d = 1; d < 256; d <<= 1) {
            const int x = (t >= d) ? sc[t - d] : 0;
            __syncthreads();
            sc[t] += x;
            __syncthreads();
        }
        if (t < NBINS_R) {
            const int ex = sc[t] - v;
            lbase[t] = ex; lcur[t] = ex;
            gbase[t] = v ? atomicAdd(&bincnt[r * NBINS_R + t], v) : 0;
        }
    }
    __syncthreads();
    for (int e = e0 + t; e < e1; e += 256) {
        const int dst = ei[NEDGE + e];
        const int src = ei[e];
        const int bin = dst >> BIN_SHIFT;
        const int pos = atomicAdd(&lcur[bin], 1);
        sorted[pos] = ((uint_t)(dst & (BIN_W - 1)) << 17) | (uint_t)src;
    }
    __syncthreads();
    const int wid = t >> 6, lane = t & 63;
    for (int b = wid; b < NBINS_R; b += 4) {
        const int cnt = lh[b], lb = lbase[b];
        uint_t* dst = binned + (size_t)(r * NBINS_R + b) * PADBIN + gbase[b];
        for (int k = lane; k < cnt; k += 64) dst[k] = sorted[lb + k];
    }
}

// ---------------- gather-aggregate: per-HALF-bin, in-LDS dst-sort, 256 threads ----
// grid (NBINS_R, 3, 2): block owns 256 nodes; scans its parent bin's edges from
// `binned`, keeps its half, sorts by local dst in LDS, then 4 waves gather rows
// (16 lanes x uint2 per row, 4 rows per wave-iteration).
__global__ void __launch_bounds__(256)
gather3_kernel(const uchar_t* __restrict__ h8_a, const uchar_t* __restrict__ h8_b,
               const uint_t* __restrict__ binned, const int* __restrict__ bincnt,
               ushort_t* __restrict__ s_ab, ushort_t* __restrict__ s_ba,
               ushort_t* __restrict__ s_aa)
{
    __shared__ int hist[GBW];
    __shared__ int off[GBW];
    __shared__ int cursor[GBW];
    __shared__ int wtot[4];
    __shared__ uint_t eLDS[EHALF];   // 22 KB
    const int b = blockIdx.x, r = blockIdx.y, hf = blockIdx.z;
    const int g = r * NBINS_R + b;
    const uchar_t* hsrc = (r == 1) ? h8_b : h8_a;
    ushort_t* s = (r == 0) ? s_ab : (r == 1) ? s_ba : s_aa;
    const int t = threadIdx.x;
    const int lane = t & 63, wid = t >> 6;
    const int ecnt = bincnt[g];
    const uint_t* bsrc = binned + (size_t)g * PADBIN;

    hist[t] = 0;
    __syncthreads();
    for (int j = t; j < ecnt; j += 256) {
        const int ld = (int)(bsrc[j] >> 17);
        if ((ld >> 8) == hf) atomicAdd(&hist[ld & (GBW - 1)], 1);
    }
    __syncthreads();
    // scan: per-wave shfl inclusive scan + 4-partial combine (3 barriers total)
    const int v = hist[t];
    int sum = v;
#pragma unroll
    for (int d = 1; d < 64; d <<= 1) {
        const int x = __shfl_up(sum, d);
        if (lane >= d) sum += x;
    }
    if (lane == 63) wtot[wid] = sum;
    __syncthreads();
    int base = 0;
    for (int q = 0; q < wid; ++q) base += wtot[q];
    const int ex = base + sum - v;   // exclusive offset
    off[t] = ex;
    cursor[t] = ex;
    __syncthreads();
    for (int j = t; j < ecnt; j += 256) {
        const uint_t p = bsrc[j];
        const int ld = (int)(p >> 17);
        if ((ld >> 8) == hf) {
            const int pos = atomicAdd(&cursor[ld & (GBW - 1)], 1);
            eLDS[pos] = p & 0x1FFFFu;
        }
    }
    __syncthreads();

    // gather: 4 waves; quarter-wave per row (16 lanes x 8 B)
    const int hl = lane & 15;            // covers fp8 bytes hl*8 .. hl*8+7
    const int sel = lane >> 4;           // 0..3: edge j+sel
    const int node0 = b * BIN_W + hf * GBW;
    for (int nl = wid; nl < GBW; nl += 4) {
        const int node = node0 + nl;
        if (node >= NA) break;           // wave-uniform
        const int o0 = off[nl], deg = hist[nl];
        const int o1 = o0 + deg;
        f32x2 a01 = {0.f, 0.f}, a23 = {0.f, 0.f}, a45 = {0.f, 0.f}, a67 = {0.f, 0.f};
        int j = o0;
        for (; j + 8 <= o1; j += 8) {
            uint2 vv[2];
#pragma unroll
            for (int q = 0; q < 2; ++q) {
                const int sE = (int)eLDS[j + 4 * q + sel];
                vv[q] = *reinterpret_cast<const uint2*>(hsrc + (size_t)sE * HD + hl * 8);
            }
#pragma unroll
            for (int q = 0; q < 2; ++q) {
                a01 += __builtin_amdgcn_cvt_pk_f32_fp8(vv[q].x, false);
                a23 += __builtin_amdgcn_cvt_pk_f32_fp8(vv[q].x, true);
                a45 += __builtin_amdgcn_cvt_pk_f32_fp8(vv[q].y, false);
                a67 += __builtin_amdgcn_cvt_pk_f32_fp8(vv[q].y, true);
            }
        }
        for (; j + 4 <= o1; j += 4) {
            const int sE = (int)eLDS[j + sel];
            const uint2 vv = *reinterpret_cast<const uint2*>(hsrc + (size_t)sE * HD + hl * 8);
            a01 += __builtin_amdgcn_cvt_pk_f32_fp8(vv.x, false);
            a23 += __builtin_amdgcn_cvt_pk_f32_fp8(vv.x, true);
            a45 += __builtin_amdgcn_cvt_pk_f32_fp8(vv.y, false);
            a67 += __builtin_amdgcn_cvt_pk_f32_fp8(vv.y, true);
        }
        if (j < o1) {
            const int rem = o1 - j;
            const int sE = (int)eLDS[min(j + sel, o1 - 1)];
            const uint2 vv = *reinterpret_cast<const uint2*>(hsrc + (size_t)sE * HD + hl * 8);
            if (sel < rem) {
                a01 += __builtin_amdgcn_cvt_pk_f32_fp8(vv.x, false);
                a23 += __builtin_amdgcn_cvt_pk_f32_fp8(vv.x, true);
                a45 += __builtin_amdgcn_cvt_pk_f32_fp8(vv.y, false);
                a67 += __builtin_amdgcn_cvt_pk_f32_fp8(vv.y, true);
            }
        }
        float f0 = a01[0], f1 = a01[1], f2 = a23[0], f3 = a23[1];
        float f4 = a45[0], f5 = a45[1], f6 = a67[0], f7 = a67[1];
        f0 += __shfl_xor(f0, 16); f0 += __shfl_xor(f0, 32);
        f1 += __shfl_xor(f1, 16); f1 += __shfl_xor(f1, 32);
        f2 += __shfl_xor(f2, 16); f2 += __shfl_xor(f2, 32);
        f3 += __shfl_xor(f3, 16); f3 += __shfl_xor(f3, 32);
        f4 += __shfl_xor(f4, 16); f4 += __shfl_xor(f4, 32);
        f5 += __shfl_xor(f5, 16); f5 += __shfl_xor(f5, 32);
        f6 += __shfl_xor(f6, 16); f6 += __shfl_xor(f6, 32);
        f7 += __shfl_xor(f7, 16); f7 += __shfl_xor(f7, 32);
        if (sel == 0) {
            const float inv = 1.0f / fmaxf((float)deg, 1.0f);
            uint4 wv;
            wv.x = pack2bf(f0 * inv, f1 * inv);
            wv.y = pack2bf(f2 * inv, f3 * inv);
            wv.z = pack2bf(f4 * inv, f5 * inv);
            wv.w = pack2bf(f6 * inv, f7 * inv);
            *reinterpret_cast<uint4*>(s + (size_t)node * HD + hl * 8) = wv;
        }
    }
}

// ---------------- MFMA fused GEMM, col-split, atomic-free, XCD-paired halves ------
template<int NSRC, int SCALE_HALF>
__device__ __forceinline__ void
mfma_body(const ushort_t* __restrict__ x0, const ushort_t* __restrict__ x1,
          const ushort_t* __restrict__ x2,
          const ushort_t* __restrict__ wtf, const float* __restrict__ bias,
          ushort_t* __restrict__ m_out, int n, int tile, int half, char* smem)
{
    ushort_t* wlds = (ushort_t*)smem;                    // NSRC * 8192 bf16 (one col-half)
    for (int i = threadIdx.x * 8; i < NSRC * 8192; i += 2048) {
        const int s = i >> 13, off = i & 8191;
        *reinterpret_cast<uint4*>(wlds + i) =
            *reinterpret_cast<const uint4*>(wtf + (size_t)s * 16384 + half * 8192 + off);
    }
    __syncthreads();

    const int l  = threadIdx.x & 63, w = threadIdx.x >> 6;
    const int lo = l & 15, hi = l >> 4;
    const int row_base = tile * 128 + w * 32;

    f32x4 acc[2][4];
    const f32x4 zero = {0.f, 0.f, 0.f, 0.f};
#pragma unroll
    for (int mi = 0; mi < 2; ++mi)
#pragma unroll
        for (int ni = 0; ni < 4; ++ni) acc[mi][ni] = zero;

#pragma unroll
    for (int s = 0; s < NSRC; ++s) {
        const ushort_t* xs = (s == 0) ? x0 : (s == 1) ? x1 : x2;
        bf16x8 a[2][4];
#pragma unroll
        for (int mi = 0; mi < 2; ++mi) {
            int r = row_base + mi * 16 + lo;
            r = min(r, n - 1);
            const ushort_t* xr = xs + (size_t)r * HD + hi * 8;
#pragma unroll
            for (int kk = 0; kk < 4; ++kk)
                a[mi][kk] = *reinterpret_cast<const bf16x8*>(xr + kk * 32);
        }
        const ushort_t* wm = wlds + s * 8192;
#pragma unroll
        for (int kk = 0; kk < 4; ++kk) {
#pragma unroll
            for (int nih = 0; nih < 4; ++nih) {
                const bf16x8 b = *reinterpret_cast<const bf16x8*>(wm + ((kk * 4 + nih) * 64 + l) * 8);
                acc[0][nih] = __builtin_amdgcn_mfma_f32_16x16x32_bf16(a[0][kk], b, acc[0][nih], 0, 0, 0);
                acc[1][nih] = __builtin_amdgcn_mfma_f32_16x16x32_bf16(a[1][kk], b, acc[1][nih], 0, 0, 0);
            }
        }
    }

#pragma unroll
    for (int nih = 0; nih < 4; ++nih) {
        const int col = half * 64 + nih * 16 + lo;
        const float bv = bias[col];
#pragma unroll
        for (int mi = 0; mi < 2; ++mi) {
            const f32x4 v = acc[mi][nih];
#pragma unroll
            for (int r = 0; r < 4; ++r) {
                const int row = row_base + mi * 16 + hi * 4 + r;
                if (row < n) {
                    float val = v[r] + bv;
                    if (SCALE_HALF) val *= 0.5f;
                    m_out[(size_t)row * HD + col] = (ushort_t)f2bf(fmaxf(val, 0.f));
                }
            }
        }
    }
}

// merged launcher. blockIdx.x decode pairs both halves of a tile on the SAME XCD:
// tile = (u>>4)*8 + (u&7), half = (u>>3)&1  -> halves are 8 linear blocks apart.
__global__ void __launch_bounds__(256)
mfma_merged(const ushort_t* __restrict__ s_ab, const ushort_t* __restrict__ h_b,
            const ushort_t* __restrict__ wt_fb, const float* __restrict__ bl_ab,
            ushort_t* __restrict__ m_b,
            const ushort_t* __restrict__ s_ba, const ushort_t* __restrict__ s_aa,
            const ushort_t* __restrict__ h_a,
            const ushort_t* __restrict__ wt_pa, const float* __restrict__ bias_pa,
            ushort_t* __restrict__ m_a)
{
    extern __shared__ char smem[];
    const int u = blockIdx.x;
    const int tile = (u >> 4) * 8 + (u & 7);
    const int half = (u >> 3) & 1;
    if (tile >= (NA + 127) / 128) return;
    if (blockIdx.y == 0)
        mfma_body<2, 0>(s_ab, h_b, nullptr, wt_fb, bl_ab, m_b, NB, tile, half, smem);
    else
        mfma_body<3, 1>(s_ba, s_aa, h_a, wt_pa, bias_pa, m_a, NA, tile, half, smem);
}

// ---------------- pooling: segment-sum over sorted batch, boundary-only atomics ---
__global__ void __launch_bounds__(256)
pool_kernel(const ushort_t* __restrict__ m_a, const ushort_t* __restrict__ m_b,
            const int* __restrict__ batch_a, const int* __restrict__ batch_b,
            float* __restrict__ pool_a, float* __restrict__ pool_b)
{
    const ushort_t* m = blockIdx.y ? m_b : m_a;
    const int* batch = blockIdx.y ? batch_b : batch_a;
    float* pool = blockIdx.y ? pool_b : pool_a;
    const int col = threadIdx.x & 127;
    const int rh = threadIdx.x >> 7;
    int row = blockIdx.x * 128 + rh * 64;
    const int rend = min(row + 64, NA);
    if (row >= rend) return;
    float acc = 0.f;
    int gcur = batch[row];
    for (; row < rend; ++row) {
        const int g = batch[row];
        if (g != gcur) {
            unsafeAtomicAdd(pool + (size_t)gcur * HD + col, acc);
            acc = 0.f; gcur = g;
        }
        acc += bf2f(m[(size_t)row * HD + col]);
    }
    unsafeAtomicAdd(pool + (size_t)gcur * HD + col, acc);
}

// ---------------- head: out = (0.5*(pa/ga + pb/gb)) @ Wout + bout ----------------
__global__ void final_kernel(const float* __restrict__ pa, const float* __restrict__ pb,
                             const float* __restrict__ ga, const float* __restrict__ gb,
                             const float* __restrict__ Wout, const float* __restrict__ bout,
                             float* __restrict__ out)
{
    const int g = blockIdx.x;
    const int lane = threadIdx.x;
    const float inva = 1.0f / fmaxf(ga[g], 1.0f);
    const float invb = 1.0f / fmaxf(gb[g], 1.0f);
    if (lane < OUTD) {
        float acc = bout[lane];
        for (int k = 0; k < HD; ++k) {
            const float x = 0.5f * (pa[g * HD + k] * inva + pb[g * HD + k] * invb);
            acc = fmaf(x, Wout[k * OUTD + lane], acc);
        }
        out[g * OUTD + lane] = acc;
    }
}

extern "C" void kernel_launch(void* const* d_in, const int* in_sizes, int n_in,
                              void* d_out, int out_size, void* d_ws, size_t ws_size,
                              hipStream_t stream)
{
    const float* x_a     = (const float*)d_in[0];
    const float* x_b     = (const float*)d_in[1];
    const int*   ei_ab   = (const int*)d_in[2];
    const int*   ei_ba   = (const int*)d_in[3];
    const int*   ei_aa   = (const int*)d_in[4];
    const int*   batch_a = (const int*)d_in[5];
    const int*   batch_b = (const int*)d_in[6];
    const float* Wemb_a  = (const float*)d_in[7];
    const float* bemb_a  = (const float*)d_in[8];
    const float* Wemb_b  = (const float*)d_in[9];
    const float* bemb_b  = (const float*)d_in[10];
    const float* Wl_ab   = (const float*)d_in[11];
    const float* bl_ab   = (const float*)d_in[12];
    const float* Wr_ab   = (const float*)d_in[13];
    const float* Wl_ba   = (const float*)d_in[14];
    const float* bl_ba   = (const float*)d_in[15];
    const float* Wr_ba   = (const float*)d_in[16];
    const float* Wl_aa   = (const float*)d_in[17];
    const float* bl_aa   = (const float*)d_in[18];
    const float* Wr_aa   = (const float*)d_in[19];
    const float* Wout    = (const float*)d_in[20];
    const float* bout    = (const float*)d_in[21];
    float* out = (float*)d_out;

    // ---------------- workspace layout ----------------
    char* p = (char*)d_ws;
    ushort_t* h_a  = (ushort_t*)p; p += (size_t)NA * HD * 2;
    ushort_t* h_b  = (ushort_t*)p; p += (size_t)NB * HD * 2;
    ushort_t* s_ab = (ushort_t*)p; p += (size_t)NB * HD * 2;
    ushort_t* s_ba = (ushort_t*)p; p += (size_t)NA * HD * 2;
    ushort_t* s_aa = (ushort_t*)p; p += (size_t)NA * HD * 2;
    ushort_t* m_a  = (ushort_t*)p; p += (size_t)NA * HD * 2;     // GEMM outputs
    ushort_t* m_b  = (ushort_t*)p; p += (size_t)NB * HD * 2;
    uchar_t* h8_a  = (uchar_t*)p;  p += (size_t)NA * HD;
    uchar_t* h8_b  = (uchar_t*)p;  p += (size_t)NB * HD;
    uint_t* binned = (uint_t*)p; p += (size_t)NBINS * PADBIN * 4;// 24.1 MB (padded)
    int* bincnt = (int*)p;  p += (NBINS + 4) * 4;
    float* pool_a = (float*)p; p += (size_t)NG * HD * 4;
    float* pool_b = (float*)p; p += (size_t)NG * HD * 4;
    float* gcnt_a = (float*)p; p += NG * 4;
    float* gcnt_b = (float*)p; p += NG * 4;
    ushort_t* wt_fb = (ushort_t*)p; p += 2 * 16384 * 2;
    ushort_t* wt_pa = (ushort_t*)p; p += 3 * 16384 * 2;
    ushort_t* wt_ea = (ushort_t*)p; p += 64 * HD * 2;
    ushort_t* wt_eb = (ushort_t*)p; p += 32 * HD * 2;
    float* bias_pa  = (float*)p;    p += HD * 4;

    const int GT = (NA + 127) / 128;                           // 782

    hipMemsetAsync(pool_a, 0, (size_t)2 * NG * HD * 4, stream);
    hipMemsetAsync(bincnt, 0, (size_t)NBINS * 4, stream);

    prep_misc_kernel<<<49, 256, 0, stream>>>(Wl_ab, Wr_ab, Wl_ba, Wl_aa, Wr_ba, Wr_aa,
                                             Wemb_a, Wemb_b, wt_fb, wt_pa, wt_ea, wt_eb,
                                             bl_ba, bl_aa, bias_pa,
                                             batch_a, batch_b, gcnt_a, gcnt_b);

    // embeddings (both node types) + fp8 table write fused
    emb2_kernel<<<dim3(GT, 2), 256, 0, stream>>>(x_a, x_b, wt_ea, wt_eb, bemb_a, bemb_b,
                                                 h_a, h_b, h8_a, h8_b);

    // ---- padded-bin partition, then fused half-bin sort+gather ----
    part3_kernel<<<dim3(ECHUNKS, 3), 256, 0, stream>>>(ei_ab, ei_ba, ei_aa, bincnt, binned);
    gather3_kernel<<<dim3(NBINS_R, 3, 2), 256, 0, stream>>>(h8_a, h8_b, binned, bincnt,
                                                            s_ab, s_ba, s_aa);

    // ---- merged MFMA GEMMs: col-split halves XCD-paired, atomic-free stores ----
    const int lds_m = 3 * 16384;   // 49152 -> 3 blocks/CU (task b uses 32KB of it)
    hipFuncSetAttribute((const void*)mfma_merged, hipFuncAttributeMaxDynamicSharedMemorySize, lds_m);
    const int GX = ((2 * GT + 15) / 16) * 16;                  // 1568
    mfma_merged<<<dim3(GX, 2), 256, lds_m, stream>>>(s_ab, h_b, wt_fb, bl_ab, m_b,
                                                     s_ba, s_aa, h_a, wt_pa, bias_pa, m_a);

    // ---- pooling: segment-sum with boundary-only atomics ----
    pool_kernel<<<dim3((NA + 127) / 128, 2), 256, 0, stream>>>(m_a, m_b, batch_a, batch_b, pool_a, pool_b);

    final_kernel<<<NG, 64, 0, stream>>>(pool_a, pool_b, gcnt_a, gcnt_b, Wout, bout, out);
}

// Round 15
// 384.971 us; speedup vs baseline: 1.0022x; 1.0022x over previous
//
#include <hip/hip_runtime.h>

#define NA 100000
#define NB 100000
#define NEDGE 1600000
#define HD 128
#define OUTD 16
#define NG 256
#define DA 64
#define DB 32

#define BIN_SHIFT 7
#define BIN_W 128
#define NBQ 782                  // ceil(100000/128) bins per relation
#define NBINS 2346               // 3 relations
#define PADBIN 3072              // padded slot per bin (mean 2046, +22 sigma)
#define EPB 8192                 // edges per block in part
#define ECHUNKS 196              // ceil(NEDGE/EPB)

typedef unsigned int uint_t;
typedef unsigned short ushort_t;
typedef unsigned char uchar_t;
typedef __bf16 bf16_t;
typedef bf16_t bf16x8 __attribute__((ext_vector_type(8)));
typedef float f32x4 __attribute__((ext_vector_type(4)));
typedef float f32x2 __attribute__((ext_vector_type(2)));

__device__ __forceinline__ float bflo(uint_t u) {
    union { uint_t i; float f; } c; c.i = u << 16; return c.f;
}
__device__ __forceinline__ float bfhi(uint_t u) {
    union { uint_t i; float f; } c; c.i = u & 0xffff0000u; return c.f;
}
__device__ __forceinline__ float bf2f(ushort_t u) {
    union { uint_t i; float f; } c; c.i = ((uint_t)u) << 16; return c.f;
}
__device__ __forceinline__ uint_t f2bf(float f) {
    union { float f; uint_t i; } c; c.f = f;
    uint_t r = c.i + 0x7FFFu + ((c.i >> 16) & 1u);
    return r >> 16;
}
__device__ __forceinline__ uint_t pack2bf(float lo, float hi) {
    return f2bf(lo) | (f2bf(hi) << 16);
}
__device__ __forceinline__ uchar_t f2fp8(float v) {
    return (uchar_t)(__builtin_amdgcn_cvt_pk_fp8_f32(v, v, 0, false) & 0xff);
}

// ---------------- weight prep (FRAGMENT-MAJOR, col-half split) + bias_pa + gcount -
__global__ void __launch_bounds__(256)
prep_misc_kernel(const float* __restrict__ Wl_ab, const float* __restrict__ Wr_ab,
                 const float* __restrict__ Wl_ba, const float* __restrict__ Wl_aa,
                 const float* __restrict__ Wr_ba, const float* __restrict__ Wr_aa,
                 const float* __restrict__ Wemb_a, const float* __restrict__ Wemb_b,
                 ushort_t* __restrict__ wt_fb, ushort_t* __restrict__ wt_pa,
                 ushort_t* __restrict__ wt_ea, ushort_t* __restrict__ wt_eb,
                 const float* __restrict__ bl_ba, const float* __restrict__ bl_aa,
                 float* __restrict__ bias_pa,
                 const int* __restrict__ batch_a, const int* __restrict__ batch_b,
                 float* __restrict__ ga, float* __restrict__ gb)
{
    const int bx = blockIdx.x;
    __align__(16) ushort_t tmp[8];
    if (bx >= 40) {
        if (bx <= 43) {                          // Wemb_a, K=64, frag-major full width
            const int id = (bx - 40) * 256 + threadIdx.x;
            const int kk = id >> 9, ni = (id >> 6) & 7, l = id & 63;
            const int col = ni * 16 + (l & 15);
            const int k0 = kk * 32 + (l >> 4) * 8;
#pragma unroll
            for (int j = 0; j < 8; ++j) tmp[j] = (ushort_t)f2bf(Wemb_a[(k0 + j) * HD + col]);
            *reinterpret_cast<uint4*>(wt_ea + (size_t)id * 8) = *reinterpret_cast<const uint4*>(tmp);
            return;
        }
        if (bx <= 45) {                          // Wemb_b, K=32, frag-major full width
            const int id = (bx - 44) * 256 + threadIdx.x;
            const int ni = id >> 6, l = id & 63;
            const int col = ni * 16 + (l & 15);
            const int k0 = (l >> 4) * 8;
#pragma unroll
            for (int j = 0; j < 8; ++j) tmp[j] = (ushort_t)f2bf(Wemb_b[(k0 + j) * HD + col]);
            *reinterpret_cast<uint4*>(wt_eb + (size_t)id * 8) = *reinterpret_cast<const uint4*>(tmp);
            return;
        }
        if (bx == 46) {
            if (threadIdx.x < HD) bias_pa[threadIdx.x] = bl_ba[threadIdx.x] + bl_aa[threadIdx.x];
            return;
        }
        // gcount via binary search (batch sorted)
        const int g = threadIdx.x;
        const int* batch = (bx == 48) ? batch_b : batch_a;
        float* outp = (bx == 48) ? gb : ga;
        const int n = NA;
        int lo0 = 0, hi0 = n;
        while (lo0 < hi0) { const int mid = (lo0 + hi0) >> 1; if (batch[mid] < g) lo0 = mid + 1; else hi0 = mid; }
        int lo1 = 0, hi1 = n;
        while (lo1 < hi1) { const int mid = (lo1 + hi1) >> 1; if (batch[mid] < g + 1) lo1 = mid + 1; else hi1 = mid; }
        outp[g] = (float)(lo1 - lo0);
        return;
    }
    const int m = bx >> 3;
    const int id = (bx & 7) * 256 + threadIdx.x;   // 0..2047
    const int kk = id >> 9, ni = (id >> 6) & 7, l = id & 63;
    const int col = ni * 16 + (l & 15);
    const int k0 = kk * 32 + (l >> 4) * 8;
    const float* src = (m == 0) ? Wl_ab : (m == 1) ? Wr_ab : (m == 2) ? Wl_ba
                     : (m == 3) ? Wl_aa : Wr_ba;
#pragma unroll
    for (int j = 0; j < 8; ++j) {
        float v = src[(k0 + j) * HD + col];
        if (m == 4) v += Wr_aa[(k0 + j) * HD + col];
        tmp[j] = (ushort_t)f2bf(v);
    }
    const int half = ni >> 2, nih = ni & 3;
    const size_t eoff = (size_t)half * 8192 + ((kk * 4 + nih) * 64 + l) * 8;
    ushort_t* dst = (m < 2) ? (wt_fb + (size_t)m * 16384) : (wt_pa + (size_t)(m - 2) * 16384);
    *reinterpret_cast<uint4*>(dst + eoff) = *reinterpret_cast<const uint4*>(tmp);
}

// ---------------- MFMA input embedding, W in LDS; writes bf16 h AND fp8 h8 --------
template<int K>
__device__ __forceinline__ void
emb_body(const float* __restrict__ x, const ushort_t* __restrict__ wtf,
         const float* __restrict__ bias, ushort_t* __restrict__ h,
         uchar_t* __restrict__ h8, int n, ushort_t* wlds)
{
    constexpr int KST = K / 32;
    for (int i = threadIdx.x * 8; i < K * HD; i += 2048)
        *reinterpret_cast<uint4*>(wlds + i) = *reinterpret_cast<const uint4*>(wtf + i);
    __syncthreads();

    const int l = threadIdx.x & 63, w = threadIdx.x >> 6;
    const int lo = l & 15, hi = l >> 4;
    const int row_base = blockIdx.x * 128 + w * 32;

    f32x4 acc[2][8];
    const f32x4 zero = {0.f, 0.f, 0.f, 0.f};
#pragma unroll
    for (int mi = 0; mi < 2; ++mi)
#pragma unroll
        for (int ni = 0; ni < 8; ++ni) acc[mi][ni] = zero;

    bf16x8 a[2][KST];
#pragma unroll
    for (int mi = 0; mi < 2; ++mi) {
        int r = row_base + mi * 16 + lo;
        r = min(r, n - 1);
        const float* xr = x + (size_t)r * K + hi * 8;
#pragma unroll
        for (int kk = 0; kk < KST; ++kk) {
            const float4 f0 = *reinterpret_cast<const float4*>(xr + kk * 32);
            const float4 f1 = *reinterpret_cast<const float4*>(xr + kk * 32 + 4);
            __align__(16) ushort_t us[8];
            us[0] = (ushort_t)f2bf(f0.x); us[1] = (ushort_t)f2bf(f0.y);
            us[2] = (ushort_t)f2bf(f0.z); us[3] = (ushort_t)f2bf(f0.w);
            us[4] = (ushort_t)f2bf(f1.x); us[5] = (ushort_t)f2bf(f1.y);
            us[6] = (ushort_t)f2bf(f1.z); us[7] = (ushort_t)f2bf(f1.w);
            a[mi][kk] = *reinterpret_cast<const bf16x8*>(us);
        }
    }
#pragma unroll
    for (int kk = 0; kk < KST; ++kk) {
#pragma unroll
        for (int ni = 0; ni < 8; ++ni) {
            const bf16x8 b = *reinterpret_cast<const bf16x8*>(wlds + ((kk * 8 + ni) * 64 + l) * 8);
            acc[0][ni] = __builtin_amdgcn_mfma_f32_16x16x32_bf16(a[0][kk], b, acc[0][ni], 0, 0, 0);
            acc[1][ni] = __builtin_amdgcn_mfma_f32_16x16x32_bf16(a[1][kk], b, acc[1][ni], 0, 0, 0);
        }
    }
#pragma unroll
    for (int ni = 0; ni < 8; ++ni) {
        const int col = ni * 16 + lo;
        const float bv = bias[col];
#pragma unroll
        for (int mi = 0; mi < 2; ++mi) {
            const f32x4 v = acc[mi][ni];
#pragma unroll
            for (int r = 0; r < 4; ++r) {
                const int row = row_base + mi * 16 + hi * 4 + r;
                if (row < n) {
                    const float val = v[r] + bv;
                    h[(size_t)row * HD + col] = (ushort_t)f2bf(val);
                    h8[(size_t)row * HD + col] = f2fp8(val);
                }
            }
        }
    }
}

__global__ void __launch_bounds__(256)
emb2_kernel(const float* __restrict__ x_a, const float* __restrict__ x_b,
            const ushort_t* __restrict__ wt_ea, const ushort_t* __restrict__ wt_eb,
            const float* __restrict__ bemb_a, const float* __restrict__ bemb_b,
            ushort_t* __restrict__ h_a, ushort_t* __restrict__ h_b,
            uchar_t* __restrict__ h8_a, uchar_t* __restrict__ h8_b)
{
    __shared__ ushort_t wlds[DA * HD];   // 16 KB (max of the two)
    if (blockIdx.y == 0) emb_body<DA>(x_a, wt_ea, bemb_a, h_a, h8_a, NA, wlds);
    else                 emb_body<DB>(x_b, wt_eb, bemb_b, h_b, h8_b, NB, wlds);
}

// ---------------- partition into PADDED quarter-bin slots (LDS-staged) ------------
// packed entry: (dst&127)<<17 | src   (src < 2^17)
__global__ void __launch_bounds__(256)
part3_kernel(const int* __restrict__ ei_ab, const int* __restrict__ ei_ba,
             const int* __restrict__ ei_aa, int* __restrict__ bincnt,
             uint_t* __restrict__ binned)
{
    __shared__ uint_t sorted[EPB];         // 32 KB
    __shared__ int lh[NBQ];
    __shared__ int lbase[NBQ];
    __shared__ int gbase[NBQ];
    __shared__ int lcur[NBQ];
    __shared__ int sc[256];
    const int r = blockIdx.y;
    const int* ei = (r == 0) ? ei_ab : (r == 1) ? ei_ba : ei_aa;
    const int t = threadIdx.x;
    for (int i = t; i < NBQ; i += 256) lh[i] = 0;
    __syncthreads();
    const int e0 = blockIdx.x * EPB;
    const int e1 = min(e0 + EPB, NEDGE);
    for (int e = e0 + t; e < e1; e += 256)
        atomicAdd(&lh[ei[NEDGE + e] >> BIN_SHIFT], 1);
    __syncthreads();
    {
        // 4 bins per thread: sequential + block scan
        int v4[4]; int s = 0;
#pragma unroll
        for (int q = 0; q < 4; ++q) {
            const int i = t * 4 + q;
            v4[q] = (i < NBQ) ? lh[i] : 0;
            s += v4[q];
        }
        sc[t] = s; __syncthreads();
        for (int d = 1; d < 256; d <<= 1) {
            const int x = (t >= d) ? sc[t - d] : 0;
            __syncthreads();
            sc[t] += x;
            __syncthreads();
        }
        int ex = sc[t] - s;
#pragma unroll
        for (int q = 0; q < 4; ++q) {
            const int i = t * 4 + q;
            if (i < NBQ) {
                lbase[i] = ex; lcur[i] = ex;
                gbase[i] = v4[q] ? atomicAdd(&bincnt[r * NBQ + i], v4[q]) : 0;
            }
            ex += v4[q];
        }
    }
    __syncthreads();
    for (int e = e0 + t; e < e1; e += 256) {
        const int dst = ei[NEDGE + e];
        const int src = ei[e];
        const int bin = dst >> BIN_SHIFT;
        const int pos = atomicAdd(&lcur[bin], 1);
        sorted[pos] = ((uint_t)(dst & (BIN_W - 1)) << 17) | (uint_t)src;
    }
    __syncthreads();
    // coalesced copy-out: 16-lane group per bin run (mean run ~10)
    const int grp = t >> 4, l16 = t & 15;
    for (int b = grp; b < NBQ; b += 16) {
        const int cnt = lh[b], lb = lbase[b];
        uint_t* dst = binned + (size_t)(r * NBQ + b) * PADBIN + gbase[b];
        for (int k = l16; k < cnt; k += 16) dst[k] = sorted[lb + k];
    }
}

// ---------------- gather-aggregate: per-quarter-bin, in-LDS dst-sort --------------
// grid (NBQ, 3): block owns 128 nodes and exactly its own ~2046 edges.
__global__ void __launch_bounds__(256)
gather3_kernel(const uchar_t* __restrict__ h8_a, const uchar_t* __restrict__ h8_b,
               const uint_t* __restrict__ binned, const int* __restrict__ bincnt,
               ushort_t* __restrict__ s_ab, ushort_t* __restrict__ s_ba,
               ushort_t* __restrict__ s_aa)
{
    __shared__ int hist[BIN_W];
    __shared__ int off[BIN_W];
    __shared__ int cursor[BIN_W];
    __shared__ int wtot[2];
    __shared__ uint_t eLDS[PADBIN];   // 12 KB
    const int b = blockIdx.x, r = blockIdx.y;
    const int g = r * NBQ + b;
    const uchar_t* hsrc = (r == 1) ? h8_b : h8_a;
    ushort_t* s = (r == 0) ? s_ab : (r == 1) ? s_ba : s_aa;
    const int t = threadIdx.x;
    const int lane = t & 63, wid = t >> 6;
    const int ecnt = bincnt[g];
    const uint_t* bsrc = binned + (size_t)g * PADBIN;

    if (t < BIN_W) hist[t] = 0;
    __syncthreads();
    for (int j = t; j < ecnt; j += 256)
        atomicAdd(&hist[bsrc[j] >> 17], 1);
    __syncthreads();
    // scan over 128 entries: 2-wave shfl scan + combine
    if (t < BIN_W) {
        const int v = hist[t];
        int sum = v;
#pragma unroll
        for (int d = 1; d < 64; d <<= 1) {
            const int x = __shfl_up(sum, d);
            if (lane >= d) sum += x;
        }
        if (lane == 63) wtot[wid] = sum;
        __syncthreads();
        const int base = (wid == 1) ? wtot[0] : 0;
        const int ex = base + sum - v;
        off[t] = ex;
        cursor[t] = ex;
    } else {
        __syncthreads();
    }
    __syncthreads();
    for (int j = t; j < ecnt; j += 256) {
        const uint_t p = bsrc[j];
        const int pos = atomicAdd(&cursor[p >> 17], 1);
        eLDS[pos] = p & 0x1FFFFu;
    }
    __syncthreads();

    // gather: 4 waves; quarter-wave per row (16 lanes x 8 B)
    const int hl = lane & 15;            // covers fp8 bytes hl*8 .. hl*8+7
    const int sel = lane >> 4;           // 0..3: edge j+sel
    const int node0 = b * BIN_W;
    for (int nl = wid; nl < BIN_W; nl += 4) {
        const int node = node0 + nl;
        if (node >= NA) break;           // wave-uniform
        const int o0 = off[nl], deg = hist[nl];
        const int o1 = o0 + deg;
        f32x2 a01 = {0.f, 0.f}, a23 = {0.f, 0.f}, a45 = {0.f, 0.f}, a67 = {0.f, 0.f};
        int j = o0;
        for (; j + 8 <= o1; j += 8) {
            uint2 vv[2];
#pragma unroll
            for (int q = 0; q < 2; ++q) {
                const int sE = (int)eLDS[j + 4 * q + sel];
                vv[q] = *reinterpret_cast<const uint2*>(hsrc + (size_t)sE * HD + hl * 8);
            }
#pragma unroll
            for (int q = 0; q < 2; ++q) {
                a01 += __builtin_amdgcn_cvt_pk_f32_fp8(vv[q].x, false);
                a23 += __builtin_amdgcn_cvt_pk_f32_fp8(vv[q].x, true);
                a45 += __builtin_amdgcn_cvt_pk_f32_fp8(vv[q].y, false);
                a67 += __builtin_amdgcn_cvt_pk_f32_fp8(vv[q].y, true);
            }
        }
        for (; j + 4 <= o1; j += 4) {
            const int sE = (int)eLDS[j + sel];
            const uint2 vv = *reinterpret_cast<const uint2*>(hsrc + (size_t)sE * HD + hl * 8);
            a01 += __builtin_amdgcn_cvt_pk_f32_fp8(vv.x, false);
            a23 += __builtin_amdgcn_cvt_pk_f32_fp8(vv.x, true);
            a45 += __builtin_amdgcn_cvt_pk_f32_fp8(vv.y, false);
            a67 += __builtin_amdgcn_cvt_pk_f32_fp8(vv.y, true);
        }
        if (j < o1) {
            const int rem = o1 - j;
            const int sE = (int)eLDS[min(j + sel, o1 - 1)];
            const uint2 vv = *reinterpret_cast<const uint2*>(hsrc + (size_t)sE * HD + hl * 8);
            if (sel < rem) {
                a01 += __builtin_amdgcn_cvt_pk_f32_fp8(vv.x, false);
                a23 += __builtin_amdgcn_cvt_pk_f32_fp8(vv.x, true);
                a45 += __builtin_amdgcn_cvt_pk_f32_fp8(vv.y, false);
                a67 += __builtin_amdgcn_cvt_pk_f32_fp8(vv.y, true);
            }
        }
        float f0 = a01[0], f1 = a01[1], f2 = a23[0], f3 = a23[1];
        float f4 = a45[0], f5 = a45[1], f6 = a67[0], f7 = a67[1];
        f0 += __shfl_xor(f0, 16); f0 += __shfl_xor(f0, 32);
        f1 += __shfl_xor(f1, 16); f1 += __shfl_xor(f1, 32);
        f2 += __shfl_xor(f2, 16); f2 += __shfl_xor(f2, 32);
        f3 += __shfl_xor(f3, 16); f3 += __shfl_xor(f3, 32);
        f4 += __shfl_xor(f4, 16); f4 += __shfl_xor(f4, 32);
        f5 += __shfl_xor(f5, 16); f5 += __shfl_xor(f5, 32);
        f6 += __shfl_xor(f6, 16); f6 += __shfl_xor(f6, 32);
        f7 += __shfl_xor(f7, 16); f7 += __shfl_xor(f7, 32);
        if (sel == 0) {
            const float inv = 1.0f / fmaxf((float)deg, 1.0f);
            uint4 wv;
            wv.x = pack2bf(f0 * inv, f1 * inv);
            wv.y = pack2bf(f2 * inv, f3 * inv);
            wv.z = pack2bf(f4 * inv, f5 * inv);
            wv.w = pack2bf(f6 * inv, f7 * inv);
            *reinterpret_cast<uint4*>(s + (size_t)node * HD + hl * 8) = wv;
        }
    }
}

// ---------------- MFMA fused GEMM, col-split, atomic-free, XCD-paired halves ------
template<int NSRC, int SCALE_HALF>
__device__ __forceinline__ void
mfma_body(const ushort_t* __restrict__ x0, const ushort_t* __restrict__ x1,
          const ushort_t* __restrict__ x2,
          const ushort_t* __restrict__ wtf, const float* __restrict__ bias,
          ushort_t* __restrict__ m_out, int n, int tile, int half, char* smem)
{
    ushort_t* wlds = (ushort_t*)smem;                    // NSRC * 8192 bf16 (one col-half)
    for (int i = threadIdx.x * 8; i < NSRC * 8192; i += 2048) {
        const int s = i >> 13, off = i & 8191;
        *reinterpret_cast<uint4*>(wlds + i) =
            *reinterpret_cast<const uint4*>(wtf + (size_t)s * 16384 + half * 8192 + off);
    }
    __syncthreads();

    const int l  = threadIdx.x & 63, w = threadIdx.x >> 6;
    const int lo = l & 15, hi = l >> 4;
    const int row_base = tile * 128 + w * 32;

    f32x4 acc[2][4];
    const f32x4 zero = {0.f, 0.f, 0.f, 0.f};
#pragma unroll
    for (int mi = 0; mi < 2; ++mi)
#pragma unroll
        for (int ni = 0; ni < 4; ++ni) acc[mi][ni] = zero;

#pragma unroll
    for (int s = 0; s < NSRC; ++s) {
        const ushort_t* xs = (s == 0) ? x0 : (s == 1) ? x1 : x2;
        bf16x8 a[2][4];
#pragma unroll
        for (int mi = 0; mi < 2; ++mi) {
            int r = row_base + mi * 16 + lo;
            r = min(r, n - 1);
            const ushort_t* xr = xs + (size_t)r * HD + hi * 8;
#pragma unroll
            for (int kk = 0; kk < 4; ++kk)
                a[mi][kk] = *reinterpret_cast<const bf16x8*>(xr + kk * 32);
        }
        const ushort_t* wm = wlds + s * 8192;
#pragma unroll
        for (int kk = 0; kk < 4; ++kk) {
#pragma unroll
            for (int nih = 0; nih < 4; ++nih) {
                const bf16x8 b = *reinterpret_cast<const bf16x8*>(wm + ((kk * 4 + nih) * 64 + l) * 8);
                acc[0][nih] = __builtin_amdgcn_mfma_f32_16x16x32_bf16(a[0][kk], b, acc[0][nih], 0, 0, 0);
                acc[1][nih] = __builtin_amdgcn_mfma_f32_16x16x32_bf16(a[1][kk], b, acc[1][nih], 0, 0, 0);
            }
        }
    }

#pragma unroll
    for (int nih = 0; nih < 4; ++nih) {
        const int col = half * 64 + nih * 16 + lo;
        const float bv = bias[col];
#pragma unroll
        for (int mi = 0; mi < 2; ++mi) {
            const f32x4 v = acc[mi][nih];
#pragma unroll
            for (int r = 0; r < 4; ++r) {
                const int row = row_base + mi * 16 + hi * 4 + r;
                if (row < n) {
                    float val = v[r] + bv;
                    if (SCALE_HALF) val *= 0.5f;
                    m_out[(size_t)row * HD + col] = (ushort_t)f2bf(fmaxf(val, 0.f));
                }
            }
        }
    }
}

// merged launcher. blockIdx.x decode pairs both halves of a tile on the SAME XCD:
// tile = (u>>4)*8 + (u&7), half = (u>>3)&1  -> halves are 8 linear blocks apart.
__global__ void __launch_bounds__(256)
mfma_merged(const ushort_t* __restrict__ s_ab, const ushort_t* __restrict__ h_b,
            const ushort_t* __restrict__ wt_fb, const float* __restrict__ bl_ab,
            ushort_t* __restrict__ m_b,
            const ushort_t* __restrict__ s_ba, const ushort_t* __restrict__ s_aa,
            const ushort_t* __restrict__ h_a,
            const ushort_t* __restrict__ wt_pa, const float* __restrict__ bias_pa,
            ushort_t* __restrict__ m_a)
{
    extern __shared__ char smem[];
    const int u = blockIdx.x;
    const int tile = (u >> 4) * 8 + (u & 7);
    const int half = (u >> 3) & 1;
    if (tile >= (NA + 127) / 128) return;
    if (blockIdx.y == 0)
        mfma_body<2, 0>(s_ab, h_b, nullptr, wt_fb, bl_ab, m_b, NB, tile, half, smem);
    else
        mfma_body<3, 1>(s_ba, s_aa, h_a, wt_pa, bias_pa, m_a, NA, tile, half, smem);
}

// ---------------- pooling: segment-sum over sorted batch, boundary-only atomics ---
__global__ void __launch_bounds__(256)
pool_kernel(const ushort_t* __restrict__ m_a, const ushort_t* __restrict__ m_b,
            const int* __restrict__ batch_a, const int* __restrict__ batch_b,
            float* __restrict__ pool_a, float* __restrict__ pool_b)
{
    const ushort_t* m = blockIdx.y ? m_b : m_a;
    const int* batch = blockIdx.y ? batch_b : batch_a;
    float* pool = blockIdx.y ? pool_b : pool_a;
    const int col = threadIdx.x & 127;
    const int rh = threadIdx.x >> 7;
    int row = blockIdx.x * 128 + rh * 64;
    const int rend = min(row + 64, NA);
    if (row >= rend) return;
    float acc = 0.f;
    int gcur = batch[row];
    for (; row < rend; ++row) {
        const int g = batch[row];
        if (g != gcur) {
            unsafeAtomicAdd(pool + (size_t)gcur * HD + col, acc);
            acc = 0.f; gcur = g;
        }
        acc += bf2f(m[(size_t)row * HD + col]);
    }
    unsafeAtomicAdd(pool + (size_t)gcur * HD + col, acc);
}

// ---------------- head: out = (0.5*(pa/ga + pb/gb)) @ Wout + bout ----------------
__global__ void final_kernel(const float* __restrict__ pa, const float* __restrict__ pb,
                             const float* __restrict__ ga, const float* __restrict__ gb,
                             const float* __restrict__ Wout, const float* __restrict__ bout,
                             float* __restrict__ out)
{
    const int g = blockIdx.x;
    const int lane = threadIdx.x;
    const float inva = 1.0f / fmaxf(ga[g], 1.0f);
    const float invb = 1.0f / fmaxf(gb[g], 1.0f);
    if (lane < OUTD) {
        float acc = bout[lane];
        for (int k = 0; k < HD; ++k) {
            const float x = 0.5f * (pa[g * HD + k] * inva + pb[g * HD + k] * invb);
            acc = fmaf(x, Wout[k * OUTD + lane], acc);
        }
        out[g * OUTD + lane] = acc;
    }
}

extern "C" void kernel_launch(void* const* d_in, const int* in_sizes, int n_in,
                              void* d_out, int out_size, void* d_ws, size_t ws_size,
                              hipStream_t stream)
{
    const float* x_a     = (const float*)d_in[0];
    const float* x_b     = (const float*)d_in[1];
    const int*   ei_ab   = (const int*)d_in[2];
    const int*   ei_ba   = (const int*)d_in[3];
    const int*   ei_aa   = (const int*)d_in[4];
    const int*   batch_a = (const int*)d_in[5];
    const int*   batch_b = (const int*)d_in[6];
    const float* Wemb_a  = (const float*)d_in[7];
    const float* bemb_a  = (const float*)d_in[8];
    const float* Wemb_b  = (const float*)d_in[9];
    const float* bemb_b  = (const float*)d_in[10];
    const float* Wl_ab   = (const float*)d_in[11];
    const float* bl_ab   = (const float*)d_in[12];
    const float* Wr_ab   = (const float*)d_in[13];
    const float* Wl_ba   = (const float*)d_in[14];
    const float* bl_ba   = (const float*)d_in[15];
    const float* Wr_ba   = (const float*)d_in[16];
    const float* Wl_aa   = (const float*)d_in[17];
    const float* bl_aa   = (const float*)d_in[18];
    const float* Wr_aa   = (const float*)d_in[19];
    const float* Wout    = (const float*)d_in[20];
    const float* bout    = (const float*)d_in[21];
    float* out = (float*)d_out;

    // ---------------- workspace layout ----------------
    char* p = (char*)d_ws;
    ushort_t* h_a  = (ushort_t*)p; p += (size_t)NA * HD * 2;
    ushort_t* h_b  = (ushort_t*)p; p += (size_t)NB * HD * 2;
    ushort_t* s_ab = (ushort_t*)p; p += (size_t)NB * HD * 2;
    ushort_t* s_ba = (ushort_t*)p; p += (size_t)NA * HD * 2;
    ushort_t* s_aa = (ushort_t*)p; p += (size_t)NA * HD * 2;
    ushort_t* m_a  = (ushort_t*)p; p += (size_t)NA * HD * 2;     // GEMM outputs
    ushort_t* m_b  = (ushort_t*)p; p += (size_t)NB * HD * 2;
    uchar_t* h8_a  = (uchar_t*)p;  p += (size_t)NA * HD;
    uchar_t* h8_b  = (uchar_t*)p;  p += (size_t)NB * HD;
    uint_t* binned = (uint_t*)p; p += (size_t)NBINS * PADBIN * 4;// 28.8 MB (padded)
    int* bincnt = (int*)p;  p += (NBINS + 4) * 4;
    float* pool_a = (float*)p; p += (size_t)NG * HD * 4;
    float* pool_b = (float*)p; p += (size_t)NG * HD * 4;
    float* gcnt_a = (float*)p; p += NG * 4;
    float* gcnt_b = (float*)p; p += NG * 4;
    ushort_t* wt_fb = (ushort_t*)p; p += 2 * 16384 * 2;
    ushort_t* wt_pa = (ushort_t*)p; p += 3 * 16384 * 2;
    ushort_t* wt_ea = (ushort_t*)p; p += 64 * HD * 2;
    ushort_t* wt_eb = (ushort_t*)p; p += 32 * HD * 2;
    float* bias_pa  = (float*)p;    p += HD * 4;

    const int GT = (NA + 127) / 128;                           // 782

    hipMemsetAsync(pool_a, 0, (size_t)2 * NG * HD * 4, stream);
    hipMemsetAsync(bincnt, 0, (size_t)NBINS * 4, stream);

    prep_misc_kernel<<<49, 256, 0, stream>>>(Wl_ab, Wr_ab, Wl_ba, Wl_aa, Wr_ba, Wr_aa,
                                             Wemb_a, Wemb_b, wt_fb, wt_pa, wt_ea, wt_eb,
                                             bl_ba, bl_aa, bias_pa,
                                             batch_a, batch_b, gcnt_a, gcnt_b);

    // embeddings (both node types) + fp8 table write fused
    emb2_kernel<<<dim3(GT, 2), 256, 0, stream>>>(x_a, x_b, wt_ea, wt_eb, bemb_a, bemb_b,
                                                 h_a, h_b, h8_a, h8_b);

    // ---- padded quarter-bin partition, then fused sort+gather ----
    part3_kernel<<<dim3(ECHUNKS, 3), 256, 0, stream>>>(ei_ab, ei_ba, ei_aa, bincnt, binned);
    gather3_kernel<<<dim3(NBQ, 3), 256, 0, stream>>>(h8_a, h8_b, binned, bincnt,
                                                     s_ab, s_ba, s_aa);

    // ---- merged MFMA GEMMs: col-split halves XCD-paired, atomic-free stores ----
    const int lds_m = 3 * 16384;   // 49152 -> 3 blocks/CU (task b uses 32KB of it)
    hipFuncSetAttribute((const void*)mfma_merged, hipFuncAttributeMaxDynamicSharedMemorySize, lds_m);
    const int GX = ((2 * GT + 15) / 16) * 16;                  // 1568
    mfma_merged<<<dim3(GX, 2), 256, lds_m, stream>>>(s_ab, h_b, wt_fb, bl_ab, m_b,
                                                     s_ba, s_aa, h_a, wt_pa, bias_pa, m_a);

    // ---- pooling: segment-sum with boundary-only atomics ----
    pool_kernel<<<dim3((NA + 127) / 128, 2), 256, 0, stream>>>(m_a, m_b, batch_a, batch_b, pool_a, pool_b);

    final_kernel<<<NG, 64, 0, stream>>>(pool_a, pool_b, gcnt_a, gcnt_b, Wout, bout, out);
}

// Round 16
// 381.452 us; speedup vs baseline: 1.0115x; 1.0092x over previous
//
#include <hip/hip_runtime.h>

#define NA 100000
#define NB 100000
#define NEDGE 1600000
#define HD 128
#define OUTD 16
#define NG 256
#define DA 64
#define DB 32

#define BIN_SHIFT 7
#define BIN_W 128
#define NBQ 782                  // ceil(100000/128) bins per relation
#define NBINS 2346               // 3 relations
#define PADBIN 3072              // padded slot per bin (mean 2046, +22 sigma)
#define EPB 8192                 // edges per block in part
#define EPT 32                   // edges per thread in part (EPB/256)
#define ECHUNKS 196              // ceil(NEDGE/EPB)

typedef unsigned int uint_t;
typedef unsigned short ushort_t;
typedef unsigned char uchar_t;
typedef __bf16 bf16_t;
typedef bf16_t bf16x8 __attribute__((ext_vector_type(8)));
typedef float f32x4 __attribute__((ext_vector_type(4)));
typedef float f32x2 __attribute__((ext_vector_type(2)));

__device__ __forceinline__ float bflo(uint_t u) {
    union { uint_t i; float f; } c; c.i = u << 16; return c.f;
}
__device__ __forceinline__ float bfhi(uint_t u) {
    union { uint_t i; float f; } c; c.i = u & 0xffff0000u; return c.f;
}
__device__ __forceinline__ float bf2f(ushort_t u) {
    union { uint_t i; float f; } c; c.i = ((uint_t)u) << 16; return c.f;
}
__device__ __forceinline__ uint_t f2bf(float f) {
    union { float f; uint_t i; } c; c.f = f;
    uint_t r = c.i + 0x7FFFu + ((c.i >> 16) & 1u);
    return r >> 16;
}
__device__ __forceinline__ uint_t pack2bf(float lo, float hi) {
    return f2bf(lo) | (f2bf(hi) << 16);
}
__device__ __forceinline__ uchar_t f2fp8(float v) {
    return (uchar_t)(__builtin_amdgcn_cvt_pk_fp8_f32(v, v, 0, false) & 0xff);
}

// ---------------- weight prep (FRAGMENT-MAJOR, col-half split) + bias_pa + gcount -
__global__ void __launch_bounds__(256)
prep_misc_kernel(const float* __restrict__ Wl_ab, const float* __restrict__ Wr_ab,
                 const float* __restrict__ Wl_ba, const float* __restrict__ Wl_aa,
                 const float* __restrict__ Wr_ba, const float* __restrict__ Wr_aa,
                 const float* __restrict__ Wemb_a, const float* __restrict__ Wemb_b,
                 ushort_t* __restrict__ wt_fb, ushort_t* __restrict__ wt_pa,
                 ushort_t* __restrict__ wt_ea, ushort_t* __restrict__ wt_eb,
                 const float* __restrict__ bl_ba, const float* __restrict__ bl_aa,
                 float* __restrict__ bias_pa,
                 const int* __restrict__ batch_a, const int* __restrict__ batch_b,
                 float* __restrict__ ga, float* __restrict__ gb)
{
    const int bx = blockIdx.x;
    __align__(16) ushort_t tmp[8];
    if (bx >= 40) {
        if (bx <= 43) {                          // Wemb_a, K=64, frag-major full width
            const int id = (bx - 40) * 256 + threadIdx.x;
            const int kk = id >> 9, ni = (id >> 6) & 7, l = id & 63;
            const int col = ni * 16 + (l & 15);
            const int k0 = kk * 32 + (l >> 4) * 8;
#pragma unroll
            for (int j = 0; j < 8; ++j) tmp[j] = (ushort_t)f2bf(Wemb_a[(k0 + j) * HD + col]);
            *reinterpret_cast<uint4*>(wt_ea + (size_t)id * 8) = *reinterpret_cast<const uint4*>(tmp);
            return;
        }
        if (bx <= 45) {                          // Wemb_b, K=32, frag-major full width
            const int id = (bx - 44) * 256 + threadIdx.x;
            const int ni = id >> 6, l = id & 63;
            const int col = ni * 16 + (l & 15);
            const int k0 = (l >> 4) * 8;
#pragma unroll
            for (int j = 0; j < 8; ++j) tmp[j] = (ushort_t)f2bf(Wemb_b[(k0 + j) * HD + col]);
            *reinterpret_cast<uint4*>(wt_eb + (size_t)id * 8) = *reinterpret_cast<const uint4*>(tmp);
            return;
        }
        if (bx == 46) {
            if (threadIdx.x < HD) bias_pa[threadIdx.x] = bl_ba[threadIdx.x] + bl_aa[threadIdx.x];
            return;
        }
        // gcount via binary search (batch sorted)
        const int g = threadIdx.x;
        const int* batch = (bx == 48) ? batch_b : batch_a;
        float* outp = (bx == 48) ? gb : ga;
        const int n = NA;
        int lo0 = 0, hi0 = n;
        while (lo0 < hi0) { const int mid = (lo0 + hi0) >> 1; if (batch[mid] < g) lo0 = mid + 1; else hi0 = mid; }
        int lo1 = 0, hi1 = n;
        while (lo1 < hi1) { const int mid = (lo1 + hi1) >> 1; if (batch[mid] < g + 1) lo1 = mid + 1; else hi1 = mid; }
        outp[g] = (float)(lo1 - lo0);
        return;
    }
    const int m = bx >> 3;
    const int id = (bx & 7) * 256 + threadIdx.x;   // 0..2047
    const int kk = id >> 9, ni = (id >> 6) & 7, l = id & 63;
    const int col = ni * 16 + (l & 15);
    const int k0 = kk * 32 + (l >> 4) * 8;
    const float* src = (m == 0) ? Wl_ab : (m == 1) ? Wr_ab : (m == 2) ? Wl_ba
                     : (m == 3) ? Wl_aa : Wr_ba;
#pragma unroll
    for (int j = 0; j < 8; ++j) {
        float v = src[(k0 + j) * HD + col];
        if (m == 4) v += Wr_aa[(k0 + j) * HD + col];
        tmp[j] = (ushort_t)f2bf(v);
    }
    const int half = ni >> 2, nih = ni & 3;
    const size_t eoff = (size_t)half * 8192 + ((kk * 4 + nih) * 64 + l) * 8;
    ushort_t* dst = (m < 2) ? (wt_fb + (size_t)m * 16384) : (wt_pa + (size_t)(m - 2) * 16384);
    *reinterpret_cast<uint4*>(dst + eoff) = *reinterpret_cast<const uint4*>(tmp);
}

// ---------------- MFMA input embedding, W in LDS; writes bf16 h AND fp8 h8 --------
template<int K>
__device__ __forceinline__ void
emb_body(const float* __restrict__ x, const ushort_t* __restrict__ wtf,
         const float* __restrict__ bias, ushort_t* __restrict__ h,
         uchar_t* __restrict__ h8, int n, ushort_t* wlds)
{
    constexpr int KST = K / 32;
    for (int i = threadIdx.x * 8; i < K * HD; i += 2048)
        *reinterpret_cast<uint4*>(wlds + i) = *reinterpret_cast<const uint4*>(wtf + i);
    __syncthreads();

    const int l = threadIdx.x & 63, w = threadIdx.x >> 6;
    const int lo = l & 15, hi = l >> 4;
    const int row_base = blockIdx.x * 128 + w * 32;

    f32x4 acc[2][8];
    const f32x4 zero = {0.f, 0.f, 0.f, 0.f};
#pragma unroll
    for (int mi = 0; mi < 2; ++mi)
#pragma unroll
        for (int ni = 0; ni < 8; ++ni) acc[mi][ni] = zero;

    bf16x8 a[2][KST];
#pragma unroll
    for (int mi = 0; mi < 2; ++mi) {
        int r = row_base + mi * 16 + lo;
        r = min(r, n - 1);
        const float* xr = x + (size_t)r * K + hi * 8;
#pragma unroll
        for (int kk = 0; kk < KST; ++kk) {
            const float4 f0 = *reinterpret_cast<const float4*>(xr + kk * 32);
            const float4 f1 = *reinterpret_cast<const float4*>(xr + kk * 32 + 4);
            __align__(16) ushort_t us[8];
            us[0] = (ushort_t)f2bf(f0.x); us[1] = (ushort_t)f2bf(f0.y);
            us[2] = (ushort_t)f2bf(f0.z); us[3] = (ushort_t)f2bf(f0.w);
            us[4] = (ushort_t)f2bf(f1.x); us[5] = (ushort_t)f2bf(f1.y);
            us[6] = (ushort_t)f2bf(f1.z); us[7] = (ushort_t)f2bf(f1.w);
            a[mi][kk] = *reinterpret_cast<const bf16x8*>(us);
        }
    }
#pragma unroll
    for (int kk = 0; kk < KST; ++kk) {
#pragma unroll
        for (int ni = 0; ni < 8; ++ni) {
            const bf16x8 b = *reinterpret_cast<const bf16x8*>(wlds + ((kk * 8 + ni) * 64 + l) * 8);
            acc[0][ni] = __builtin_amdgcn_mfma_f32_16x16x32_bf16(a[0][kk], b, acc[0][ni], 0, 0, 0);
            acc[1][ni] = __builtin_amdgcn_mfma_f32_16x16x32_bf16(a[1][kk], b, acc[1][ni], 0, 0, 0);
        }
    }
#pragma unroll
    for (int ni = 0; ni < 8; ++ni) {
        const int col = ni * 16 + lo;
        const float bv = bias[col];
#pragma unroll
        for (int mi = 0; mi < 2; ++mi) {
            const f32x4 v = acc[mi][ni];
#pragma unroll
            for (int r = 0; r < 4; ++r) {
                const int row = row_base + mi * 16 + hi * 4 + r;
                if (row < n) {
                    const float val = v[r] + bv;
                    h[(size_t)row * HD + col] = (ushort_t)f2bf(val);
                    h8[(size_t)row * HD + col] = f2fp8(val);
                }
            }
        }
    }
}

__global__ void __launch_bounds__(256)
emb2_kernel(const float* __restrict__ x_a, const float* __restrict__ x_b,
            const ushort_t* __restrict__ wt_ea, const ushort_t* __restrict__ wt_eb,
            const float* __restrict__ bemb_a, const float* __restrict__ bemb_b,
            ushort_t* __restrict__ h_a, ushort_t* __restrict__ h_b,
            uchar_t* __restrict__ h8_a, uchar_t* __restrict__ h8_b)
{
    __shared__ ushort_t wlds[DA * HD];   // 16 KB (max of the two)
    if (blockIdx.y == 0) emb_body<DA>(x_a, wt_ea, bemb_a, h_a, h8_a, NA, wlds);
    else                 emb_body<DB>(x_b, wt_eb, bemb_b, h_b, h8_b, NB, wlds);
}

// ---------------- partition into PADDED quarter-bin slots (LDS-staged) ------------
// packed entry: (dst&127)<<17 | src   (src < 2^17)
// dst column is read ONCE into registers (EPT=32 edges per thread).
__global__ void __launch_bounds__(256)
part3_kernel(const int* __restrict__ ei_ab, const int* __restrict__ ei_ba,
             const int* __restrict__ ei_aa, int* __restrict__ bincnt,
             uint_t* __restrict__ binned)
{
    __shared__ uint_t sorted[EPB];         // 32 KB
    __shared__ int lh[NBQ];
    __shared__ int lbase[NBQ];
    __shared__ int gbase[NBQ];
    __shared__ int lcur[NBQ];
    __shared__ int sc[256];
    const int r = blockIdx.y;
    const int* ei = (r == 0) ? ei_ab : (r == 1) ? ei_ba : ei_aa;
    const int t = threadIdx.x;
    for (int i = t; i < NBQ; i += 256) lh[i] = 0;
    __syncthreads();
    const int e0 = blockIdx.x * EPB;
    const int ecnt = min(EPB, NEDGE - e0);
    int dcache[EPT];
#pragma unroll
    for (int k = 0; k < EPT; ++k) {
        const int e = t + k * 256;
        if (e < ecnt) {
            const int dst = ei[NEDGE + e0 + e];
            dcache[k] = dst;
            atomicAdd(&lh[dst >> BIN_SHIFT], 1);
        } else dcache[k] = -1;
    }
    __syncthreads();
    {
        // 4 bins per thread: sequential + block scan
        int v4[4]; int s = 0;
#pragma unroll
        for (int q = 0; q < 4; ++q) {
            const int i = t * 4 + q;
            v4[q] = (i < NBQ) ? lh[i] : 0;
            s += v4[q];
        }
        sc[t] = s; __syncthreads();
        for (int d = 1; d < 256; d <<= 1) {
            const int x = (t >= d) ? sc[t - d] : 0;
            __syncthreads();
            sc[t] += x;
            __syncthreads();
        }
        int ex = sc[t] - s;
#pragma unroll
        for (int q = 0; q < 4; ++q) {
            const int i = t * 4 + q;
            if (i < NBQ) {
                lbase[i] = ex; lcur[i] = ex;
                gbase[i] = v4[q] ? atomicAdd(&bincnt[r * NBQ + i], v4[q]) : 0;
            }
            ex += v4[q];
        }
    }
    __syncthreads();
#pragma unroll
    for (int k = 0; k < EPT; ++k) {
        const int dst = dcache[k];
        if (dst >= 0) {
            const int src = ei[e0 + t + k * 256];
            const int bin = dst >> BIN_SHIFT;
            const int pos = atomicAdd(&lcur[bin], 1);
            sorted[pos] = ((uint_t)(dst & (BIN_W - 1)) << 17) | (uint_t)src;
        }
    }
    __syncthreads();
    // coalesced copy-out: 16-lane group per bin run (mean run ~10)
    const int grp = t >> 4, l16 = t & 15;
    for (int b = grp; b < NBQ; b += 16) {
        const int cnt = lh[b], lb = lbase[b];
        uint_t* dst = binned + (size_t)(r * NBQ + b) * PADBIN + gbase[b];
        for (int k = l16; k < cnt; k += 16) dst[k] = sorted[lb + k];
    }
}

// ---------------- gather-aggregate: per-quarter-bin, in-LDS dst-sort --------------
// grid (NBQ, 3): block owns 128 nodes and exactly its own ~2046 edges.
__global__ void __launch_bounds__(256)
gather3_kernel(const uchar_t* __restrict__ h8_a, const uchar_t* __restrict__ h8_b,
               const uint_t* __restrict__ binned, const int* __restrict__ bincnt,
               ushort_t* __restrict__ s_ab, ushort_t* __restrict__ s_ba,
               ushort_t* __restrict__ s_aa)
{
    __shared__ int hist[BIN_W];
    __shared__ int off[BIN_W];
    __shared__ int cursor[BIN_W];
    __shared__ int wtot[2];
    __shared__ uint_t eLDS[PADBIN];   // 12 KB
    const int b = blockIdx.x, r = blockIdx.y;
    const int g = r * NBQ + b;
    const uchar_t* hsrc = (r == 1) ? h8_b : h8_a;
    ushort_t* s = (r == 0) ? s_ab : (r == 1) ? s_ba : s_aa;
    const int t = threadIdx.x;
    const int lane = t & 63, wid = t >> 6;
    const int ecnt = bincnt[g];
    const uint_t* bsrc = binned + (size_t)g * PADBIN;

    if (t < BIN_W) hist[t] = 0;
    __syncthreads();
    for (int j = t; j < ecnt; j += 256)
        atomicAdd(&hist[bsrc[j] >> 17], 1);
    __syncthreads();
    // scan over 128 entries: 2-wave shfl scan + combine
    if (t < BIN_W) {
        const int v = hist[t];
        int sum = v;
#pragma unroll
        for (int d = 1; d < 64; d <<= 1) {
            const int x = __shfl_up(sum, d);
            if (lane >= d) sum += x;
        }
        if (lane == 63) wtot[wid] = sum;
        __syncthreads();
        const int base = (wid == 1) ? wtot[0] : 0;
        const int ex = base + sum - v;
        off[t] = ex;
        cursor[t] = ex;
    } else {
        __syncthreads();
    }
    __syncthreads();
    for (int j = t; j < ecnt; j += 256) {
        const uint_t p = bsrc[j];
        const int pos = atomicAdd(&cursor[p >> 17], 1);
        eLDS[pos] = p & 0x1FFFFu;
    }
    __syncthreads();

    // gather: 4 waves; quarter-wave per row (16 lanes x 8 B); 16-edge unroll
    const int hl = lane & 15;            // covers fp8 bytes hl*8 .. hl*8+7
    const int sel = lane >> 4;           // 0..3: edge j+sel
    const int node0 = b * BIN_W;
    for (int nl = wid; nl < BIN_W; nl += 4) {
        const int node = node0 + nl;
        if (node >= NA) break;           // wave-uniform
        const int o0 = off[nl], deg = hist[nl];
        const int o1 = o0 + deg;
        f32x2 a01 = {0.f, 0.f}, a23 = {0.f, 0.f}, a45 = {0.f, 0.f}, a67 = {0.f, 0.f};
        int j = o0;
        for (; j + 16 <= o1; j += 16) {
            uint2 vv[4];
#pragma unroll
            for (int q = 0; q < 4; ++q) {
                const int sE = (int)eLDS[j + 4 * q + sel];
                vv[q] = *reinterpret_cast<const uint2*>(hsrc + (size_t)sE * HD + hl * 8);
            }
#pragma unroll
            for (int q = 0; q < 4; ++q) {
                a01 += __builtin_amdgcn_cvt_pk_f32_fp8(vv[q].x, false);
                a23 += __builtin_amdgcn_cvt_pk_f32_fp8(vv[q].x, true);
                a45 += __builtin_amdgcn_cvt_pk_f32_fp8(vv[q].y, false);
                a67 += __builtin_amdgcn_cvt_pk_f32_fp8(vv[q].y, true);
            }
        }
        for (; j + 8 <= o1; j += 8) {
            uint2 vv[2];
#pragma unroll
            for (int q = 0; q < 2; ++q) {
                const int sE = (int)eLDS[j + 4 * q + sel];
                vv[q] = *reinterpret_cast<const uint2*>(hsrc + (size_t)sE * HD + hl * 8);
            }
#pragma unroll
            for (int q = 0; q < 2; ++q) {
                a01 += __builtin_amdgcn_cvt_pk_f32_fp8(vv[q].x, false);
                a23 += __builtin_amdgcn_cvt_pk_f32_fp8(vv[q].x, true);
                a45 += __builtin_amdgcn_cvt_pk_f32_fp8(vv[q].y, false);
                a67 += __builtin_amdgcn_cvt_pk_f32_fp8(vv[q].y, true);
            }
        }
        for (; j + 4 <= o1; j += 4) {
            const int sE = (int)eLDS[j + sel];
            const uint2 vv = *reinterpret_cast<const uint2*>(hsrc + (size_t)sE * HD + hl * 8);
            a01 += __builtin_amdgcn_cvt_pk_f32_fp8(vv.x, false);
            a23 += __builtin_amdgcn_cvt_pk_f32_fp8(vv.x, true);
            a45 += __builtin_amdgcn_cvt_pk_f32_fp8(vv.y, false);
            a67 += __builtin_amdgcn_cvt_pk_f32_fp8(vv.y, true);
        }
        if (j < o1) {
            const int rem = o1 - j;
            const int sE = (int)eLDS[min(j + sel, o1 - 1)];
            const uint2 vv = *reinterpret_cast<const uint2*>(hsrc + (size_t)sE * HD + hl * 8);
            if (sel < rem) {
                a01 += __builtin_amdgcn_cvt_pk_f32_fp8(vv.x, false);
                a23 += __builtin_amdgcn_cvt_pk_f32_fp8(vv.x, true);
                a45 += __builtin_amdgcn_cvt_pk_f32_fp8(vv.y, false);
                a67 += __builtin_amdgcn_cvt_pk_f32_fp8(vv.y, true);
            }
        }
        float f0 = a01[0], f1 = a01[1], f2 = a23[0], f3 = a23[1];
        float f4 = a45[0], f5 = a45[1], f6 = a67[0], f7 = a67[1];
        f0 += __shfl_xor(f0, 16); f0 += __shfl_xor(f0, 32);
        f1 += __shfl_xor(f1, 16); f1 += __shfl_xor(f1, 32);
        f2 += __shfl_xor(f2, 16); f2 += __shfl_xor(f2, 32);
        f3 += __shfl_xor(f3, 16); f3 += __shfl_xor(f3, 32);
        f4 += __shfl_xor(f4, 16); f4 += __shfl_xor(f4, 32);
        f5 += __shfl_xor(f5, 16); f5 += __shfl_xor(f5, 32);
        f6 += __shfl_xor(f6, 16); f6 += __shfl_xor(f6, 32);
        f7 += __shfl_xor(f7, 16); f7 += __shfl_xor(f7, 32);
        if (sel == 0) {
            const float inv = 1.0f / fmaxf((float)deg, 1.0f);
            uint4 wv;
            wv.x = pack2bf(f0 * inv, f1 * inv);
            wv.y = pack2bf(f2 * inv, f3 * inv);
            wv.z = pack2bf(f4 * inv, f5 * inv);
            wv.w = pack2bf(f6 * inv, f7 * inv);
            *reinterpret_cast<uint4*>(s + (size_t)node * HD + hl * 8) = wv;
        }
    }
}

// ---------------- MFMA fused GEMM, col-split, atomic-free, XCD-paired halves ------
template<int NSRC, int SCALE_HALF>
__device__ __forceinline__ void
mfma_body(const ushort_t* __restrict__ x0, const ushort_t* __restrict__ x1,
          const ushort_t* __restrict__ x2,
          const ushort_t* __restrict__ wtf, const float* __restrict__ bias,
          ushort_t* __restrict__ m_out, int n, int tile, int half, char* smem)
{
    ushort_t* wlds = (ushort_t*)smem;                    // NSRC * 8192 bf16 (one col-half)
    for (int i = threadIdx.x * 8; i < NSRC * 8192; i += 2048) {
        const int s = i >> 13, off = i & 8191;
        *reinterpret_cast<uint4*>(wlds + i) =
            *reinterpret_cast<const uint4*>(wtf + (size_t)s * 16384 + half * 8192 + off);
    }
    __syncthreads();

    const int l  = threadIdx.x & 63, w = threadIdx.x >> 6;
    const int lo = l & 15, hi = l >> 4;
    const int row_base = tile * 128 + w * 32;

    f32x4 acc[2][4];
    const f32x4 zero = {0.f, 0.f, 0.f, 0.f};
#pragma unroll
    for (int mi = 0; mi < 2; ++mi)
#pragma unroll
        for (int ni = 0; ni < 4; ++ni) acc[mi][ni] = zero;

#pragma unroll
    for (int s = 0; s < NSRC; ++s) {
        const ushort_t* xs = (s == 0) ? x0 : (s == 1) ? x1 : x2;
        bf16x8 a[2][4];
#pragma unroll
        for (int mi = 0; mi < 2; ++mi) {
            int r = row_base + mi * 16 + lo;
            r = min(r, n - 1);
            const ushort_t* xr = xs + (size_t)r * HD + hi * 8;
#pragma unroll
            for (int kk = 0; kk < 4; ++kk)
                a[mi][kk] = *reinterpret_cast<const bf16x8*>(xr + kk * 32);
        }
        const ushort_t* wm = wlds + s * 8192;
#pragma unroll
        for (int kk = 0; kk < 4; ++kk) {
#pragma unroll
            for (int nih = 0; nih < 4; ++nih) {
                const bf16x8 b = *reinterpret_cast<const bf16x8*>(wm + ((kk * 4 + nih) * 64 + l) * 8);
                acc[0][nih] = __builtin_amdgcn_mfma_f32_16x16x32_bf16(a[0][kk], b, acc[0][nih], 0, 0, 0);
                acc[1][nih] = __builtin_amdgcn_mfma_f32_16x16x32_bf16(a[1][kk], b, acc[1][nih], 0, 0, 0);
            }
        }
    }

#pragma unroll
    for (int nih = 0; nih < 4; ++nih) {
        const int col = half * 64 + nih * 16 + lo;
        const float bv = bias[col];
#pragma unroll
        for (int mi = 0; mi < 2; ++mi) {
            const f32x4 v = acc[mi][nih];
#pragma unroll
            for (int r = 0; r < 4; ++r) {
                const int row = row_base + mi * 16 + hi * 4 + r;
                if (row < n) {
                    float val = v[r] + bv;
                    if (SCALE_HALF) val *= 0.5f;
                    m_out[(size_t)row * HD + col] = (ushort_t)f2bf(fmaxf(val, 0.f));
                }
            }
        }
    }
}

// merged launcher. blockIdx.x decode pairs both halves of a tile on the SAME XCD:
// tile = (u>>4)*8 + (u&7), half = (u>>3)&1  -> halves are 8 linear blocks apart.
__global__ void __launch_bounds__(256)
mfma_merged(const ushort_t* __restrict__ s_ab, const ushort_t* __restrict__ h_b,
            const ushort_t* __restrict__ wt_fb, const float* __restrict__ bl_ab,
            ushort_t* __restrict__ m_b,
            const ushort_t* __restrict__ s_ba, const ushort_t* __restrict__ s_aa,
            const ushort_t* __restrict__ h_a,
            const ushort_t* __restrict__ wt_pa, const float* __restrict__ bias_pa,
            ushort_t* __restrict__ m_a)
{
    extern __shared__ char smem[];
    const int u = blockIdx.x;
    const int tile = (u >> 4) * 8 + (u & 7);
    const int half = (u >> 3) & 1;
    if (tile >= (NA + 127) / 128) return;
    if (blockIdx.y == 0)
        mfma_body<2, 0>(s_ab, h_b, nullptr, wt_fb, bl_ab, m_b, NB, tile, half, smem);
    else
        mfma_body<3, 1>(s_ba, s_aa, h_a, wt_pa, bias_pa, m_a, NA, tile, half, smem);
}

// ---------------- pooling: segment-sum over sorted batch, boundary-only atomics ---
__global__ void __launch_bounds__(256)
pool_kernel(const ushort_t* __restrict__ m_a, const ushort_t* __restrict__ m_b,
            const int* __restrict__ batch_a, const int* __restrict__ batch_b,
            float* __restrict__ pool_a, float* __restrict__ pool_b)
{
    const ushort_t* m = blockIdx.y ? m_b : m_a;
    const int* batch = blockIdx.y ? batch_b : batch_a;
    float* pool = blockIdx.y ? pool_b : pool_a;
    const int col = threadIdx.x & 127;
    const int rh = threadIdx.x >> 7;
    int row = blockIdx.x * 128 + rh * 64;
    const int rend = min(row + 64, NA);
    if (row >= rend) return;
    float acc = 0.f;
    int gcur = batch[row];
    for (; row < rend; ++row) {
        const int g = batch[row];
        if (g != gcur) {
            unsafeAtomicAdd(pool + (size_t)gcur * HD + col, acc);
            acc = 0.f; gcur = g;
        }
        acc += bf2f(m[(size_t)row * HD + col]);
    }
    unsafeAtomicAdd(pool + (size_t)gcur * HD + col, acc);
}

// ---------------- head: out = (0.5*(pa/ga + pb/gb)) @ Wout + bout ----------------
__global__ void final_kernel(const float* __restrict__ pa, const float* __restrict__ pb,
                             const float* __restrict__ ga, const float* __restrict__ gb,
                             const float* __restrict__ Wout, const float* __restrict__ bout,
                             float* __restrict__ out)
{
    const int g = blockIdx.x;
    const int lane = threadIdx.x;
    const float inva = 1.0f / fmaxf(ga[g], 1.0f);
    const float invb = 1.0f / fmaxf(gb[g], 1.0f);
    if (lane < OUTD) {
        float acc = bout[lane];
        for (int k = 0; k < HD; ++k) {
            const float x = 0.5f * (pa[g * HD + k] * inva + pb[g * HD + k] * invb);
            acc = fmaf(x, Wout[k * OUTD + lane], acc);
        }
        out[g * OUTD + lane] = acc;
    }
}

extern "C" void kernel_launch(void* const* d_in, const int* in_sizes, int n_in,
                              void* d_out, int out_size, void* d_ws, size_t ws_size,
                              hipStream_t stream)
{
    const float* x_a     = (const float*)d_in[0];
    const float* x_b     = (const float*)d_in[1];
    const int*   ei_ab   = (const int*)d_in[2];
    const int*   ei_ba   = (const int*)d_in[3];
    const int*   ei_aa   = (const int*)d_in[4];
    const int*   batch_a = (const int*)d_in[5];
    const int*   batch_b = (const int*)d_in[6];
    const float* Wemb_a  = (const float*)d_in[7];
    const float* bemb_a  = (const float*)d_in[8];
    const float* Wemb_b  = (const float*)d_in[9];
    const float* bemb_b  = (const float*)d_in[10];
    const float* Wl_ab   = (const float*)d_in[11];
    const float* bl_ab   = (const float*)d_in[12];
    const float* Wr_ab   = (const float*)d_in[13];
    const float* Wl_ba   = (const float*)d_in[14];
    const float* bl_ba   = (const float*)d_in[15];
    const float* Wr_ba   = (const float*)d_in[16];
    const float* Wl_aa   = (const float*)d_in[17];
    const float* bl_aa   = (const float*)d_in[18];
    const float* Wr_aa   = (const float*)d_in[19];
    const float* Wout    = (const float*)d_in[20];
    const float* bout    = (const float*)d_in[21];
    float* out = (float*)d_out;

    // ---------------- workspace layout ----------------
    char* p = (char*)d_ws;
    ushort_t* h_a  = (ushort_t*)p; p += (size_t)NA * HD * 2;
    ushort_t* h_b  = (ushort_t*)p; p += (size_t)NB * HD * 2;
    ushort_t* s_ab = (ushort_t*)p; p += (size_t)NB * HD * 2;
    ushort_t* s_ba = (ushort_t*)p; p += (size_t)NA * HD * 2;
    ushort_t* s_aa = (ushort_t*)p; p += (size_t)NA * HD * 2;
    ushort_t* m_a  = (ushort_t*)p; p += (size_t)NA * HD * 2;     // GEMM outputs
    ushort_t* m_b  = (ushort_t*)p; p += (size_t)NB * HD * 2;
    uchar_t* h8_a  = (uchar_t*)p;  p += (size_t)NA * HD;
    uchar_t* h8_b  = (uchar_t*)p;  p += (size_t)NB * HD;
    uint_t* binned = (uint_t*)p; p += (size_t)NBINS * PADBIN * 4;// 28.8 MB (padded)
    int* bincnt = (int*)p;  p += (NBINS + 4) * 4;
    float* pool_a = (float*)p; p += (size_t)NG * HD * 4;
    float* pool_b = (float*)p; p += (size_t)NG * HD * 4;
    float* gcnt_a = (float*)p; p += NG * 4;
    float* gcnt_b = (float*)p; p += NG * 4;
    ushort_t* wt_fb = (ushort_t*)p; p += 2 * 16384 * 2;
    ushort_t* wt_pa = (ushort_t*)p; p += 3 * 16384 * 2;
    ushort_t* wt_ea = (ushort_t*)p; p += 64 * HD * 2;
    ushort_t* wt_eb = (ushort_t*)p; p += 32 * HD * 2;
    float* bias_pa  = (float*)p;    p += HD * 4;

    const int GT = (NA + 127) / 128;                           // 782

    hipMemsetAsync(pool_a, 0, (size_t)2 * NG * HD * 4, stream);
    hipMemsetAsync(bincnt, 0, (size_t)NBINS * 4, stream);

    prep_misc_kernel<<<49, 256, 0, stream>>>(Wl_ab, Wr_ab, Wl_ba, Wl_aa, Wr_ba, Wr_aa,
                                             Wemb_a, Wemb_b, wt_fb, wt_pa, wt_ea, wt_eb,
                                             bl_ba, bl_aa, bias_pa,
                                             batch_a, batch_b, gcnt_a, gcnt_b);

    // embeddings (both node types) + fp8 table write fused
    emb2_kernel<<<dim3(GT, 2), 256, 0, stream>>>(x_a, x_b, wt_ea, wt_eb, bemb_a, bemb_b,
                                                 h_a, h_b, h8_a, h8_b);

    // ---- padded quarter-bin partition, then fused sort+gather ----
    part3_kernel<<<dim3(ECHUNKS, 3), 256, 0, stream>>>(ei_ab, ei_ba, ei_aa, bincnt, binned);
    gather3_kernel<<<dim3(NBQ, 3), 256, 0, stream>>>(h8_a, h8_b, binned, bincnt,
                                                     s_ab, s_ba, s_aa);

    // ---- merged MFMA GEMMs: col-split halves XCD-paired, atomic-free stores ----
    const int lds_m = 3 * 16384;   // 49152 -> 3 blocks/CU (task b uses 32KB of it)
    hipFuncSetAttribute((const void*)mfma_merged, hipFuncAttributeMaxDynamicSharedMemorySize, lds_m);
    const int GX = ((2 * GT + 15) / 16) * 16;                  // 1568
    mfma_merged<<<dim3(GX, 2), 256, lds_m, stream>>>(s_ab, h_b, wt_fb, bl_ab, m_b,
                                                     s_ba, s_aa, h_a, wt_pa, bias_pa, m_a);

    // ---- pooling: segment-sum with boundary-only atomics ----
    pool_kernel<<<dim3((NA + 127) / 128, 2), 256, 0, stream>>>(m_a, m_b, batch_a, batch_b, pool_a, pool_b);

    final_kernel<<<NG, 64, 0, stream>>>(pool_a, pool_b, gcnt_a, gcnt_b, Wout, bout, out);
}